// Round 1
// baseline (573.800 us; speedup 1.0000x reference)
//
#include <hip/hip_runtime.h>
#include <stdint.h>

#define BB 4
#define HH 256
#define WW 256
#define CC 128
#define NN 32
#define NPIX (HH*WW)            // 65536
#define RANK 52428u             // 0-based order-stat index: 0.8*(65536-1)
#define TOTAL_PAIRS 1984.0f     // B * N*(N-1)/2

// workspace byte offsets
#define OFF_SMALL   0            // u32[32]: [0]=merged, [1..4]=cnt[b], [8+2b]=T, [9+2b]=r2, [16+b]=thr_key
#define OFF_GT      4096         // B*N*C floats   = 64 KiB
#define OFF_GNORM   (OFF_GT + BB*NN*CC*4)        // B*N floats (padded)
#define OFF_KEYS    (OFF_GNORM + 4096)           // B*NPIX u32 = 1 MiB
#define OFF_HIST    (OFF_KEYS + BB*NPIX*4)       // B*65536 u32 = 1 MiB
#define OFF_CAND    (OFF_HIST + BB*65536*4)      // B*NPIX u32 = 1 MiB
#define OFF_P       (OFF_CAND + BB*NPIX*4)       // B*NPIX i32 = 1 MiB

// ---------------- K0: gather center features + |g|^2 ----------------
__global__ void k_gather(const float* __restrict__ feat, const int* __restrict__ centers,
                         float* __restrict__ gt, float* __restrict__ gnorm) {
    int b = blockIdx.x / NN, n = blockIdx.x % NN;
    int cy = centers[(b*NN + n)*2 + 0];
    int cx = centers[(b*NN + n)*2 + 1];
    int c = threadIdx.x; // 128 threads
    float v = feat[((size_t)b*NPIX + cy*WW + cx)*CC + c];
    gt[(b*NN + n)*CC + c] = v;
    __shared__ float s[128];
    s[c] = v*v;
    __syncthreads();
    for (int off = 64; off > 0; off >>= 1) {
        if (c < off) s[c] += s[c+off];
        __syncthreads();
    }
    if (c == 0) gnorm[b*NN + n] = s[0];
}

// ---------------- K1: per-pixel min squared distance -> sortable key ----------------
__global__ __launch_bounds__(256) void k_d2min(const float* __restrict__ feat,
        const float* __restrict__ gt, const float* __restrict__ gnorm,
        uint32_t* __restrict__ keys) {
    int b = blockIdx.y;
    int p = blockIdx.x*256 + threadIdx.x;
    const float4* f4 = (const float4*)(feat + ((size_t)b*NPIX + p)*CC);
    const float4* g4 = (const float4*)(gt + b*NN*CC);   // wave-uniform -> scalar loads
    float acc[NN];
    #pragma unroll
    for (int n = 0; n < NN; n++) acc[n] = 0.f;
    float fn = 0.f;
    #pragma unroll 4
    for (int k = 0; k < CC/4; k++) {
        float4 f = f4[k];
        fn = fmaf(f.x,f.x, fmaf(f.y,f.y, fmaf(f.z,f.z, fmaf(f.w,f.w, fn))));
        #pragma unroll
        for (int n = 0; n < NN; n++) {
            float4 g = g4[n*(CC/4) + k];
            acc[n] = fmaf(f.x,g.x, fmaf(f.y,g.y, fmaf(f.z,g.z, fmaf(f.w,g.w, acc[n]))));
        }
    }
    float m = 3.4e38f;
    #pragma unroll
    for (int n = 0; n < NN; n++) {
        float d2 = fn + gnorm[b*NN + n] - 2.f*acc[n];
        m = fminf(m, d2);
    }
    if (!(m > 0.f)) m = 0.f;   // clamp negatives AND -0.0 to +0.0 (bit-order safety)
    keys[(size_t)b*NPIX + p] = __float_as_uint(m);
}

// ---------------- K2: 16-bit-prefix histogram ----------------
__global__ void k_hist(const uint32_t* __restrict__ keys, uint32_t* __restrict__ hist) {
    int b = blockIdx.y;
    int p = blockIdx.x*256 + threadIdx.x;
    uint32_t k = keys[b*NPIX + p];
    atomicAdd(&hist[b*65536 + (k >> 16)], 1u);
}

// ---------------- K3: find the 16-bit bin containing rank RANK ----------------
__global__ void k_selbin(const uint32_t* __restrict__ hist, uint32_t* __restrict__ sm) {
    int b = blockIdx.x;
    const uint32_t* h = hist + b*65536;
    __shared__ uint32_t seg[256];
    __shared__ uint32_t pre[256];
    int t = threadIdx.x;
    uint32_t s = 0;
    for (int i = 0; i < 256; i++) s += h[t*256 + i];
    seg[t] = s;
    __syncthreads();
    if (t == 0) { uint32_t c = 0; for (int i = 0; i < 256; i++) { pre[i] = c; c += seg[i]; } }
    __syncthreads();
    uint32_t r = RANK;
    if (pre[t] <= r && r < pre[t] + seg[t]) {
        uint32_t c = pre[t];
        for (int i = 0; i < 256; i++) {
            uint32_t hc = h[t*256 + i];
            if (r < c + hc) { sm[8 + b*2] = (uint32_t)(t*256 + i); sm[9 + b*2] = r - c; break; }
            c += hc;
        }
    }
}

// ---------------- K4: collect candidates in the target bin ----------------
__global__ void k_collect(const uint32_t* __restrict__ keys, uint32_t* __restrict__ sm,
                          uint32_t* __restrict__ cand) {
    int b = blockIdx.y;
    int p = blockIdx.x*256 + threadIdx.x;
    uint32_t k = keys[b*NPIX + p];
    if ((k >> 16) == sm[8 + b*2]) {
        uint32_t pos = atomicAdd(&sm[1 + b], 1u);
        cand[b*NPIX + pos] = k;
    }
}

// ---------------- K5: exact rank among candidates (duplicate-safe) ----------------
__global__ void k_selfinal(const uint32_t* __restrict__ cand, uint32_t* __restrict__ sm) {
    int b = blockIdx.x;
    uint32_t n = sm[1 + b];
    uint32_t r2 = sm[9 + b*2];
    const uint32_t* cb = cand + b*NPIX;
    for (uint32_t i = threadIdx.x; i < n; i += blockDim.x) {
        uint32_t v = cb[i];
        uint32_t less = 0, eq = 0;
        for (uint32_t j = 0; j < n; j++) { uint32_t w = cb[j]; less += (w < v); eq += (w == v); }
        if (less <= r2 && r2 < less + eq) sm[16 + b] = v;   // all writers write same value
    }
}

// ---------------- K6: init union-find parents from mask ----------------
__global__ void k_initp(const uint32_t* __restrict__ keys, const uint32_t* __restrict__ sm,
                        int* __restrict__ P) {
    int b = blockIdx.y;
    int p = blockIdx.x*256 + threadIdx.x;
    uint32_t thr = sm[16 + b];
    P[b*NPIX + p] = (keys[b*NPIX + p] >= thr) ? p : -1;
}

// ---------------- K7: union-find CCL (8-connected) ----------------
__device__ __forceinline__ int uf_find(int* P, int x) {
    while (true) {
        int p = P[x];
        if (p == x) return x;
        int gp = P[p];
        if (gp != p) P[x] = gp;   // path halving (benign race; parents only point to valid ancestors)
        x = gp;
    }
}

__device__ __forceinline__ void uf_unite(int* P, int a, int b) {
    while (true) {
        a = uf_find(P, a);
        b = uf_find(P, b);
        if (a == b) return;
        if (a > b) { int t = a; a = b; b = t; }
        int old = atomicCAS(&P[b], b, a);   // device-scope: safe across XCDs
        if (old == b) return;
        b = old;                            // fresh value from the atomic -> guaranteed progress
    }
}

__global__ void k_union(int* __restrict__ Pg) {
    int b = blockIdx.y;
    int p = blockIdx.x*256 + threadIdx.x;
    int* P = Pg + b*NPIX;
    if (P[p] == -1) return;
    int y = p >> 8, x = p & 255;
    if (x > 0      && P[p-1]      != -1) uf_unite(P, p, p-1);
    if (y > 0) {
        if (          P[p-WW]     != -1) uf_unite(P, p, p-WW);
        if (x > 0  && P[p-WW-1]   != -1) uf_unite(P, p, p-WW-1);
        if (x < WW-1 && P[p-WW+1] != -1) uf_unite(P, p, p-WW+1);
    }
}

// ---------------- K8: count merged pairs at centers ----------------
__global__ void k_pairs(const int* __restrict__ centers, int* __restrict__ Pg,
                        uint32_t* __restrict__ sm) {
    int b = blockIdx.x;
    __shared__ int ids[NN];
    int t = threadIdx.x;  // 64 threads = 1 wave
    int* P = Pg + b*NPIX;
    if (t < NN) {
        int cy = centers[(b*NN + t)*2 + 0];
        int cx = centers[(b*NN + t)*2 + 1];
        int p = cy*WW + cx;
        int id = P[p];
        if (id != -1) {  // read-only find (post-kernel-boundary: coherent)
            int x = p;
            while (true) { int q = P[x]; if (q == x) break; x = q; }
            id = x;
        }
        ids[t] = id;
    }
    __syncthreads();
    int cnt = 0;
    if (t < NN && ids[t] != -1) {
        for (int j = t+1; j < NN; j++) cnt += (ids[j] == ids[t]);
    }
    for (int off = 32; off > 0; off >>= 1) cnt += __shfl_down(cnt, off);
    if (t == 0) atomicAdd(&sm[0], (uint32_t)cnt);
}

// ---------------- K9: final rate ----------------
__global__ void k_finish(const uint32_t* __restrict__ sm, float* __restrict__ out) {
    out[0] = (float)sm[0] / TOTAL_PAIRS;
}

extern "C" void kernel_launch(void* const* d_in, const int* in_sizes, int n_in,
                              void* d_out, int out_size, void* d_ws, size_t ws_size,
                              hipStream_t stream) {
    const float* feat   = (const float*)d_in[0];
    const int* centers  = (const int*)d_in[1];
    float* out          = (float*)d_out;
    char* ws            = (char*)d_ws;

    float*    gt    = (float*)(ws + OFF_GT);
    float*    gnorm = (float*)(ws + OFF_GNORM);
    uint32_t* keys  = (uint32_t*)(ws + OFF_KEYS);
    uint32_t* hist  = (uint32_t*)(ws + OFF_HIST);
    uint32_t* cand  = (uint32_t*)(ws + OFF_CAND);
    int*      P     = (int*)(ws + OFF_P);
    uint32_t* sm    = (uint32_t*)(ws + OFF_SMALL);

    // zero the counters + histogram (ws is poisoned 0xAA before every call)
    hipMemsetAsync(sm, 0, 128, stream);
    hipMemsetAsync(hist, 0, (size_t)BB*65536*4, stream);

    dim3 gridPix(NPIX/256, BB);

    k_gather  <<<BB*NN, CC, 0, stream>>>(feat, centers, gt, gnorm);
    k_d2min   <<<gridPix, 256, 0, stream>>>(feat, gt, gnorm, keys);
    k_hist    <<<gridPix, 256, 0, stream>>>(keys, hist);
    k_selbin  <<<BB, 256, 0, stream>>>(hist, sm);
    k_collect <<<gridPix, 256, 0, stream>>>(keys, sm, cand);
    k_selfinal<<<BB, 256, 0, stream>>>(cand, sm);
    k_initp   <<<gridPix, 256, 0, stream>>>(keys, sm, P);
    k_union   <<<gridPix, 256, 0, stream>>>(P);
    k_pairs   <<<BB, 64, 0, stream>>>(centers, P, sm);
    k_finish  <<<1, 1, 0, stream>>>(sm, out);
}

// Round 2
// 333.658 us; speedup vs baseline: 1.7197x; 1.7197x over previous
//
#include <hip/hip_runtime.h>
#include <stdint.h>

#define BB 4
#define HH 256
#define WW 256
#define CC 128
#define NN 32
#define NPIX (HH*WW)            // 65536
#define RANK 52428u             // 0-based order-stat index: 0.8*(65536-1) exactly
#define TOTAL_PAIRS 1984.0f     // B * N*(N-1)/2

// workspace byte offsets
// sm layout (u32): [0]=merged, [4+b]=T1, [8+b]=r1, [12+b]=bin16, [16+b]=r2, [20+b]=thr_key
#define OFF_SMALL   0
#define OFF_GT      4096                          // B*N*C floats = 64 KiB
#define OFF_GNORM   (OFF_GT + BB*NN*CC*4)         // B*N floats (padded to 4 KiB)
#define OFF_KEYS    (OFF_GNORM + 4096)            // B*NPIX u32 = 1 MiB
#define OFF_H1      (OFF_KEYS + BB*NPIX*4)        // B*256 u32 = 4 KiB
#define OFF_H2      (OFF_H1 + 4096)               // B*256 u32 = 4 KiB
#define OFF_H3      (OFF_H2 + 4096)               // B*65536 u32 = 1 MiB
#define OFF_P       (OFF_H3 + BB*65536*4)         // B*NPIX i32 = 1 MiB

// ---------------- K0: gather center features + |g|^2 ----------------
__global__ void k_gather(const float* __restrict__ feat, const int* __restrict__ centers,
                         float* __restrict__ gt, float* __restrict__ gnorm) {
    int b = blockIdx.x / NN, n = blockIdx.x % NN;
    int cy = centers[(b*NN + n)*2 + 0];
    int cx = centers[(b*NN + n)*2 + 1];
    int c = threadIdx.x; // 128 threads
    float v = feat[((size_t)b*NPIX + cy*WW + cx)*CC + c];
    gt[(b*NN + n)*CC + c] = v;
    __shared__ float s[128];
    s[c] = v*v;
    __syncthreads();
    for (int off = 64; off > 0; off >>= 1) {
        if (c < off) s[c] += s[c+off];
        __syncthreads();
    }
    if (c == 0) gnorm[b*NN + n] = s[0];
}

// ---------------- K1: per-pixel min squared distance -> sortable key ----------------
__global__ __launch_bounds__(256) void k_d2min(const float* __restrict__ feat,
        const float* __restrict__ gt, const float* __restrict__ gnorm,
        uint32_t* __restrict__ keys) {
    int b = blockIdx.y;
    int p = blockIdx.x*256 + threadIdx.x;
    const float4* f4 = (const float4*)(feat + ((size_t)b*NPIX + p)*CC);
    const float4* g4 = (const float4*)(gt + b*NN*CC);   // wave-uniform -> scalar loads
    float acc[NN];
    #pragma unroll
    for (int n = 0; n < NN; n++) acc[n] = 0.f;
    float fn = 0.f;
    #pragma unroll 4
    for (int k = 0; k < CC/4; k++) {
        float4 f = f4[k];
        fn = fmaf(f.x,f.x, fmaf(f.y,f.y, fmaf(f.z,f.z, fmaf(f.w,f.w, fn))));
        #pragma unroll
        for (int n = 0; n < NN; n++) {
            float4 g = g4[n*(CC/4) + k];
            acc[n] = fmaf(f.x,g.x, fmaf(f.y,g.y, fmaf(f.z,g.z, fmaf(f.w,g.w, acc[n]))));
        }
    }
    float m = 3.4e38f;
    #pragma unroll
    for (int n = 0; n < NN; n++) {
        float d2 = fn + gnorm[b*NN + n] - 2.f*acc[n];
        m = fminf(m, d2);
    }
    if (!(m > 0.f)) m = 0.f;   // clamp negatives AND -0.0 to +0.0 (bit-order safety)
    keys[(size_t)b*NPIX + p] = __float_as_uint(m);
}

// ---------------- K2a: 256-bin histogram of key>>24 (LDS-staged) ----------------
__global__ __launch_bounds__(256) void k_hist1(const uint32_t* __restrict__ keys,
                                               uint32_t* __restrict__ h1) {
    __shared__ uint32_t lh[256];
    int b = blockIdx.y, t = threadIdx.x;
    lh[t] = 0;
    __syncthreads();
    int p0 = blockIdx.x*1024 + t;   // 64 blocks/batch, 4 pixels/thread
    #pragma unroll
    for (int i = 0; i < 4; i++) {
        uint32_t k = keys[b*NPIX + p0 + i*256];
        atomicAdd(&lh[k >> 24], 1u);
    }
    __syncthreads();
    uint32_t v = lh[t];
    if (v) atomicAdd(&h1[b*256 + t], v);
}

// ---------------- K3a: select coarse bin T1 containing RANK ----------------
__global__ void k_sel1(const uint32_t* __restrict__ h1, uint32_t* __restrict__ sm) {
    int b = blockIdx.x, t = threadIdx.x;
    __shared__ uint32_t cnt[256];
    __shared__ uint32_t pre[256];
    cnt[t] = h1[b*256 + t];
    __syncthreads();
    if (t == 0) { uint32_t c = 0; for (int i = 0; i < 256; i++) { pre[i] = c; c += cnt[i]; } }
    __syncthreads();
    uint32_t r = RANK;
    if (pre[t] <= r && r < pre[t] + cnt[t]) { sm[4 + b] = (uint32_t)t; sm[8 + b] = r - pre[t]; }
}

// ---------------- K2b: 256-bin histogram of bits 16..23 among prefix==T1 ----------------
__global__ __launch_bounds__(256) void k_hist2(const uint32_t* __restrict__ keys,
        const uint32_t* __restrict__ sm, uint32_t* __restrict__ h2) {
    __shared__ uint32_t lh[256];
    int b = blockIdx.y, t = threadIdx.x;
    lh[t] = 0;
    __syncthreads();
    uint32_t T1 = sm[4 + b];
    int p0 = blockIdx.x*1024 + t;
    #pragma unroll
    for (int i = 0; i < 4; i++) {
        uint32_t k = keys[b*NPIX + p0 + i*256];
        if ((k >> 24) == T1) atomicAdd(&lh[(k >> 16) & 255u], 1u);
    }
    __syncthreads();
    uint32_t v = lh[t];
    if (v) atomicAdd(&h2[b*256 + t], v);
}

// ---------------- K3b: select second-level bin -> bin16, r2 ----------------
__global__ void k_sel2(const uint32_t* __restrict__ h2, uint32_t* __restrict__ sm) {
    int b = blockIdx.x, t = threadIdx.x;
    __shared__ uint32_t cnt[256];
    __shared__ uint32_t pre[256];
    cnt[t] = h2[b*256 + t];
    __syncthreads();
    if (t == 0) { uint32_t c = 0; for (int i = 0; i < 256; i++) { pre[i] = c; c += cnt[i]; } }
    __syncthreads();
    uint32_t r = sm[8 + b];
    if (pre[t] <= r && r < pre[t] + cnt[t]) {
        sm[12 + b] = (sm[4 + b] << 8) | (uint32_t)t;
        sm[16 + b] = r - pre[t];
    }
}

// ---------------- K2c: 65536-bin histogram of low 16 bits among top16==bin16 ----------------
__global__ __launch_bounds__(256) void k_hist3(const uint32_t* __restrict__ keys,
        const uint32_t* __restrict__ sm, uint32_t* __restrict__ h3) {
    int b = blockIdx.y;
    int p = blockIdx.x*256 + threadIdx.x;
    uint32_t bin16 = sm[12 + b];
    uint32_t k = keys[b*NPIX + p];
    if ((k >> 16) == bin16) atomicAdd(&h3[b*65536 + (k & 0xffffu)], 1u);
}

// ---------------- K3c: scan 65536 bins for rank r2 -> exact threshold key ----------------
__global__ void k_sel3(const uint32_t* __restrict__ h3, uint32_t* __restrict__ sm) {
    int b = blockIdx.x, t = threadIdx.x;
    const uint32_t* h = h3 + b*65536;
    __shared__ uint32_t seg[256];
    __shared__ uint32_t pre[256];
    uint32_t s = 0;
    for (int i = 0; i < 256; i++) s += h[t*256 + i];
    seg[t] = s;
    __syncthreads();
    if (t == 0) { uint32_t c = 0; for (int i = 0; i < 256; i++) { pre[i] = c; c += seg[i]; } }
    __syncthreads();
    uint32_t r = sm[16 + b];
    if (pre[t] <= r && r < pre[t] + seg[t]) {
        uint32_t c = pre[t];
        for (int i = 0; i < 256; i++) {
            uint32_t hc = h[t*256 + i];
            if (r < c + hc) {
                sm[20 + b] = (sm[12 + b] << 16) | (uint32_t)(t*256 + i);
                break;
            }
            c += hc;
        }
    }
}

// ---------------- K6: init union-find parents from mask ----------------
__global__ void k_initp(const uint32_t* __restrict__ keys, const uint32_t* __restrict__ sm,
                        int* __restrict__ P) {
    int b = blockIdx.y;
    int p = blockIdx.x*256 + threadIdx.x;
    uint32_t thr = sm[20 + b];
    P[b*NPIX + p] = (keys[b*NPIX + p] >= thr) ? p : -1;
}

// ---------------- K7: union-find CCL (8-connected) ----------------
__device__ __forceinline__ int uf_find(int* P, int x) {
    while (true) {
        int p = P[x];
        if (p == x) return x;
        int gp = P[p];
        if (gp != p) P[x] = gp;   // path halving (benign race; parents only point to valid ancestors)
        x = gp;
    }
}

__device__ __forceinline__ void uf_unite(int* P, int a, int b) {
    while (true) {
        a = uf_find(P, a);
        b = uf_find(P, b);
        if (a == b) return;
        if (a > b) { int t = a; a = b; b = t; }
        int old = atomicCAS(&P[b], b, a);   // device-scope: safe across XCDs
        if (old == b) return;
        b = old;                            // fresh value from the atomic -> guaranteed progress
    }
}

__global__ void k_union(int* __restrict__ Pg) {
    int b = blockIdx.y;
    int p = blockIdx.x*256 + threadIdx.x;
    int* P = Pg + b*NPIX;
    if (P[p] == -1) return;
    int y = p >> 8, x = p & 255;
    if (x > 0      && P[p-1]      != -1) uf_unite(P, p, p-1);
    if (y > 0) {
        if (          P[p-WW]     != -1) uf_unite(P, p, p-WW);
        if (x > 0  && P[p-WW-1]   != -1) uf_unite(P, p, p-WW-1);
        if (x < WW-1 && P[p-WW+1] != -1) uf_unite(P, p, p-WW+1);
    }
}

// ---------------- K8: count merged pairs at centers ----------------
__global__ void k_pairs(const int* __restrict__ centers, int* __restrict__ Pg,
                        uint32_t* __restrict__ sm) {
    int b = blockIdx.x;
    __shared__ int ids[NN];
    int t = threadIdx.x;  // 64 threads = 1 wave
    int* P = Pg + b*NPIX;
    if (t < NN) {
        int cy = centers[(b*NN + t)*2 + 0];
        int cx = centers[(b*NN + t)*2 + 1];
        int p = cy*WW + cx;
        int id = P[p];
        if (id != -1) {  // read-only find (post-kernel-boundary: coherent)
            int x = p;
            while (true) { int q = P[x]; if (q == x) break; x = q; }
            id = x;
        }
        ids[t] = id;
    }
    __syncthreads();
    int cnt = 0;
    if (t < NN && ids[t] != -1) {
        for (int j = t+1; j < NN; j++) cnt += (ids[j] == ids[t]);
    }
    for (int off = 32; off > 0; off >>= 1) cnt += __shfl_down(cnt, off);
    if (t == 0) atomicAdd(&sm[0], (uint32_t)cnt);
}

// ---------------- K9: final rate ----------------
__global__ void k_finish(const uint32_t* __restrict__ sm, float* __restrict__ out) {
    out[0] = (float)sm[0] / TOTAL_PAIRS;
}

extern "C" void kernel_launch(void* const* d_in, const int* in_sizes, int n_in,
                              void* d_out, int out_size, void* d_ws, size_t ws_size,
                              hipStream_t stream) {
    const float* feat   = (const float*)d_in[0];
    const int* centers  = (const int*)d_in[1];
    float* out          = (float*)d_out;
    char* ws            = (char*)d_ws;

    float*    gt    = (float*)(ws + OFF_GT);
    float*    gnorm = (float*)(ws + OFF_GNORM);
    uint32_t* keys  = (uint32_t*)(ws + OFF_KEYS);
    uint32_t* h1    = (uint32_t*)(ws + OFF_H1);
    uint32_t* h2    = (uint32_t*)(ws + OFF_H2);
    uint32_t* h3    = (uint32_t*)(ws + OFF_H3);
    int*      P     = (int*)(ws + OFF_P);
    uint32_t* sm    = (uint32_t*)(ws + OFF_SMALL);

    // zero counters + histograms (h1,h2,h3 are contiguous)
    hipMemsetAsync(sm, 0, 128, stream);
    hipMemsetAsync(h1, 0, 4096 + 4096 + (size_t)BB*65536*4, stream);

    dim3 gridPix(NPIX/256, BB);
    dim3 gridH(NPIX/1024, BB);

    k_gather <<<BB*NN, CC, 0, stream>>>(feat, centers, gt, gnorm);
    k_d2min  <<<gridPix, 256, 0, stream>>>(feat, gt, gnorm, keys);
    k_hist1  <<<gridH, 256, 0, stream>>>(keys, h1);
    k_sel1   <<<BB, 256, 0, stream>>>(h1, sm);
    k_hist2  <<<gridH, 256, 0, stream>>>(keys, sm, h2);
    k_sel2   <<<BB, 256, 0, stream>>>(h2, sm);
    k_hist3  <<<gridPix, 256, 0, stream>>>(keys, sm, h3);
    k_sel3   <<<BB, 256, 0, stream>>>(h3, sm);
    k_initp  <<<gridPix, 256, 0, stream>>>(keys, sm, P);
    k_union  <<<gridPix, 256, 0, stream>>>(P);
    k_pairs  <<<BB, 64, 0, stream>>>(centers, P, sm);
    k_finish <<<1, 1, 0, stream>>>(sm, out);
}